// Round 6
// baseline (384.846 us; speedup 1.0000x reference)
//
#include <hip/hip_runtime.h>
#include <stdint.h>

// ---------------------------------------------------------------------------
// Types / helpers
// ---------------------------------------------------------------------------
typedef __bf16 bf16x8 __attribute__((ext_vector_type(8)));
typedef float  f32x4  __attribute__((ext_vector_type(4)));

__device__ __forceinline__ unsigned short f2bf(float f) {
  union { float f; unsigned int u; } a; a.f = f;
  unsigned int r = a.u + 0x7FFFu + ((a.u >> 16) & 1u);   // RNE
  return (unsigned short)(r >> 16);
}

__device__ __forceinline__ unsigned short f2bf_fast(float f) {
  union { __bf16 b; unsigned short u; } v; v.b = (__bf16)f; return v.u;
}

// async global->LDS, 16B per lane. LDS dest must be wave-uniform base + lane*16.
__device__ __forceinline__ void cp16(const void* g, void* l) {
  auto g1 = reinterpret_cast<__attribute__((address_space(1))) unsigned int*>(
      reinterpret_cast<uintptr_t>(g));
  auto l3 = reinterpret_cast<__attribute__((address_space(3))) unsigned int*>(
      reinterpret_cast<uintptr_t>(l));
  __builtin_amdgcn_global_load_lds(g1, l3, 16, 0, 0);
}

// ---------------------------------------------------------------------------
// fp32 -> bf16 convert of all 4 weight matrices in one launch.
// ---------------------------------------------------------------------------
__global__ __launch_bounds__(256) void cvt_all(
    const float* __restrict__ s0, const float* __restrict__ s1,
    const float* __restrict__ s2, const float* __restrict__ s3,
    unsigned short* __restrict__ d0, unsigned short* __restrict__ d1,
    unsigned short* __restrict__ d2, unsigned short* __restrict__ d3) {
  int i = (blockIdx.x * 256 + threadIdx.x) * 4;
  const float* src; unsigned short* dst; int off;
  if (i < 3145728)       { src = s0; dst = d0; off = 0; }
  else if (i < 4194304)  { src = s1; dst = d1; off = 3145728; }
  else if (i < 8388608)  { src = s2; dst = d2; off = 4194304; }
  else                   { src = s3; dst = d3; off = 8388608; }
  i -= off;
  float4 v = *(const float4*)(src + i);
  union { unsigned short u[4]; uint2 p; } o;
  o.u[0] = f2bf(v.x); o.u[1] = f2bf(v.y); o.u[2] = f2bf(v.z); o.u[3] = f2bf(v.w);
  *(uint2*)(dst + i) = o.p;
}

// ---------------------------------------------------------------------------
// LayerNorm (E=1024), fp32 in -> bf16 out, PLUS seeds the next split-K GEMM's
// accumulator: seed_out[row,:] = x[row,:] + seed_bias[:].
// ---------------------------------------------------------------------------
__global__ __launch_bounds__(256) void ln_bf16_seed(
    const float* __restrict__ x,
    const float* __restrict__ g,
    const float* __restrict__ bta,
    unsigned short* __restrict__ out,
    const float* __restrict__ seed_bias,
    float* __restrict__ seed_out) {
  const int row = blockIdx.x, t = threadIdx.x;
  const float4 v = *(const float4*)(x + (size_t)row * 1024 + t * 4);
  {
    float4 sb = *(const float4*)(seed_bias + t * 4);
    float4 sv;
    sv.x = v.x + sb.x; sv.y = v.y + sb.y; sv.z = v.z + sb.z; sv.w = v.w + sb.w;
    *(float4*)(seed_out + (size_t)row * 1024 + t * 4) = sv;
  }
  float s1 = v.x + v.y + v.z + v.w;
  float s2 = v.x*v.x + v.y*v.y + v.z*v.z + v.w*v.w;
  #pragma unroll
  for (int off = 1; off < 64; off <<= 1) {
    s1 += __shfl_xor(s1, off, 64);
    s2 += __shfl_xor(s2, off, 64);
  }
  __shared__ float r1[4], r2[4];
  if ((t & 63) == 0) { r1[t >> 6] = s1; r2[t >> 6] = s2; }
  __syncthreads();
  s1 = r1[0] + r1[1] + r1[2] + r1[3];
  s2 = r2[0] + r2[1] + r2[2] + r2[3];
  const float mean = s1 * (1.0f / 1024.0f);
  const float var  = s2 * (1.0f / 1024.0f) - mean * mean;
  const float rstd = rsqrtf(var + 1e-5f);
  const float4 gv = *(const float4*)(g + t * 4);
  const float4 bv = *(const float4*)(bta + t * 4);
  union { unsigned short u[4]; uint2 p; } o;
  o.u[0] = f2bf((v.x - mean) * rstd * gv.x + bv.x);
  o.u[1] = f2bf((v.y - mean) * rstd * gv.y + bv.y);
  o.u[2] = f2bf((v.z - mean) * rstd * gv.z + bv.z);
  o.u[3] = f2bf((v.w - mean) * rstd * gv.w + bv.w);
  *(uint2*)(out + (size_t)row * 1024 + t * 4) = o.p;
}

// ---------------------------------------------------------------------------
// Pipelined GEMM core. BK=32 batches, NBUF-deep LDS ring (8 KB per tile per
// buffer). Paired-row LDS layout: line l (128 B) holds rows {2l, 2l+1}; the
// four 16 B chunks of each 32-elem row sit at slot (chunk ^ (l&3)). Both the
// cp16 staging (wave-uniform + lane*16) and the frag ds_read_b128 are
// bank-balanced (2 lanes per 4-bank group).
// K-loop: wait vmcnt(4*(NBUF-1)) steady state (never 0 until tail), raw
// s_barrier, 16 MFMA, s_barrier, issue batch it+NBUF.
// MODE 0 = bf16 v+bias; MODE 2 = bf16 relu(v+bias); MODE 4 = atomic fp32 +=v.
// ---------------------------------------------------------------------------
template <int MODE, int NBUF>
__device__ __forceinline__ void gemm_core(
    const unsigned short* __restrict__ A,
    const unsigned short* __restrict__ Bt,
    const float* __restrict__ bias,
    void* __restrict__ outp,
    int N, int K, int kbeg, int kend,
    unsigned short* As, unsigned short* Bs) {   // each NBUF*4096 elems
  const int tid = threadIdx.x;
  const int wave = tid >> 6, lane = tid & 63;
  const int q = lane >> 4, c = lane & 15;
  const int wm = (wave & 1) << 6, wn = (wave >> 1) << 6;
  const int m0 = blockIdx.x << 7, n0 = blockIdx.y << 7;

  // staging map: thread -> (row, chunk) of a 128x32 tile half (64 rows/iter)
  const int row0 = ((tid >> 3) << 1) | ((tid >> 2) & 1);
  const int gcol = ((tid & 3) ^ ((tid >> 3) & 3)) << 3;
  const unsigned short* gA = A  + (size_t)(m0 + row0) * K + gcol + kbeg;
  const unsigned short* gB = Bt + (size_t)(n0 + row0) * K + gcol + kbeg;
  const size_t rstep64 = (size_t)64 * K;

  const int nit = (kend - kbeg) >> 5;

  auto issue = [&](int it) {
    const int buf = it % NBUF;
    const int k0 = it << 5;
    unsigned short* lA = As + buf * 4096 + tid * 8;
    unsigned short* lB = Bs + buf * 4096 + tid * 8;
    cp16(gA + k0, lA);
    cp16(gA + rstep64 + k0, lA + 2048);
    cp16(gB + k0, lB);
    cp16(gB + rstep64 + k0, lB + 2048);
  };

  // frag read offsets (elements)
  const int laneoff = ((c >> 1) << 6) + ((c & 1) << 5) + ((q ^ ((c >> 1) & 3)) << 3);
  const int aoff = (wm << 5) + laneoff;
  const int boff = (wn << 5) + laneoff;

  const f32x4 fzero = {0.f, 0.f, 0.f, 0.f};
  f32x4 acc[4][4];
  #pragma unroll
  for (int i = 0; i < 4; i++)
    #pragma unroll
    for (int j = 0; j < 4; j++) acc[i][j] = fzero;

  issue(0);
  if (nit > 1) issue(1);
  if (NBUF >= 3 && nit > 2) issue(2);

  for (int it = 0; it < nit; ++it) {
    if (NBUF >= 3) {
      if (it + 2 < nit)      asm volatile("s_waitcnt vmcnt(8)" ::: "memory");
      else if (it + 1 < nit) asm volatile("s_waitcnt vmcnt(4)" ::: "memory");
      else                   asm volatile("s_waitcnt vmcnt(0)" ::: "memory");
    } else {
      if (it + 1 < nit) asm volatile("s_waitcnt vmcnt(4)" ::: "memory");
      else              asm volatile("s_waitcnt vmcnt(0)" ::: "memory");
    }
    asm volatile("s_barrier" ::: "memory");

    const unsigned short* cA = As + (it % NBUF) * 4096;
    const unsigned short* cB = Bs + (it % NBUF) * 4096;
    bf16x8 af[4], bf[4];
    #pragma unroll
    for (int i = 0; i < 4; i++) af[i] = *(const bf16x8*)&cA[aoff + i * 512];
    #pragma unroll
    for (int j = 0; j < 4; j++) bf[j] = *(const bf16x8*)&cB[boff + j * 512];
    #pragma unroll
    for (int i = 0; i < 4; i++)
      #pragma unroll
      for (int j = 0; j < 4; j++)
        acc[i][j] = __builtin_amdgcn_mfma_f32_16x16x32_bf16(af[i], bf[j], acc[i][j], 0, 0, 0);

    asm volatile("s_barrier" ::: "memory");
    if (it + NBUF < nit) issue(it + NBUF);
  }

  if (MODE == 4) {
    float* op = (float*)outp;
    #pragma unroll
    for (int i = 0; i < 4; i++) {
      #pragma unroll
      for (int r = 0; r < 4; r++) {
        const int row = m0 + wm + i * 16 + q * 4 + r;
        #pragma unroll
        for (int j = 0; j < 4; j++) {
          const int col = n0 + wn + j * 16 + c;
          atomicAdd(op + (size_t)row * N + col, acc[i][j][r]);
        }
      }
    }
  } else {
    float bj[4];
    #pragma unroll
    for (int j = 0; j < 4; j++) bj[j] = bias[n0 + wn + j * 16 + c];
    #pragma unroll
    for (int i = 0; i < 4; i++) {
      #pragma unroll
      for (int r = 0; r < 4; r++) {
        const int row = m0 + wm + i * 16 + q * 4 + r;
        #pragma unroll
        for (int j = 0; j < 4; j++) {
          const int col = n0 + wn + j * 16 + c;
          const size_t idx = (size_t)row * N + col;
          float v = acc[i][j][r] + bj[j];
          if (MODE == 0) ((unsigned short*)outp)[idx] = f2bf(v);
          else           ((unsigned short*)outp)[idx] = f2bf(fmaxf(v, 0.f));
        }
      }
    }
  }
}

template <int MODE, int NBUF, int MINW>
__global__ __launch_bounds__(256, MINW) void gemm_k(
    const unsigned short* __restrict__ A,
    const unsigned short* __restrict__ Bt,
    const float* __restrict__ bias,
    void* __restrict__ outp,
    int N, int K) {
  __shared__ __align__(16) unsigned short As[NBUF * 4096];
  __shared__ __align__(16) unsigned short Bs[NBUF * 4096];
  gemm_core<MODE, NBUF>(A, Bt, bias, outp, N, K, 0, K, As, Bs);
}

// split-K: chunk CH per z-slice, atomicAdd into pre-seeded fp32 output
template <int NBUF, int MINW>
__global__ __launch_bounds__(256, MINW) void gemm_splitk(
    const unsigned short* __restrict__ A,
    const unsigned short* __restrict__ Bt,
    float* __restrict__ outp,
    int N, int K, int CH) {
  __shared__ __align__(16) unsigned short As[NBUF * 4096];
  __shared__ __align__(16) unsigned short Bs[NBUF * 4096];
  const int kbeg = blockIdx.z * CH;
  int kend = kbeg + CH; if (kend > K) kend = K;
  gemm_core<4, NBUF>(A, Bt, nullptr, outp, N, K, kbeg, kend, As, Bs);
}

// ---------------------------------------------------------------------------
// Flash attention, causal + rel_pos bias — pipelined.
// K tiles: triple-buffered LDS via cp16 (issued post-barrier, consumed two
// iterations later). V tiles: prefetched one tile ahead into ping-pong VGPRs,
// ds_written (transposed+swizzled) into double-buffered Vs overlapped with
// QK^T/softmax. Raw barriers + vmcnt(4)/lgkmcnt(0), no full drains.
// ---------------------------------------------------------------------------
__global__ __launch_bounds__(256, 2) void attn_flash(
    const unsigned short* __restrict__ qkv,   // [4096, 3072] bf16 (q|k|v)
    const float* __restrict__ rel_pos,        // [16, 2048] fp32
    unsigned short* __restrict__ o) {         // [4096, 1024] bf16 ([b,s,h,d])
  __shared__ __align__(16) unsigned short Qs[128 * 64];
  __shared__ __align__(16) unsigned short Ks[3 * 64 * 64];
  __shared__ __align__(16) unsigned short Vs[2 * 64 * 64];   // transposed [d][kt]
  __shared__ __align__(16) unsigned short Ps[4][32 * 64];
  __shared__ float rps[1024];                                // rel_pos[h,:]*log2e

  const int tid = threadIdx.x;
  const int wave = tid >> 6, lane = tid & 63;
  const int q = lane >> 4, c = lane & 15;

  const int lid = blockIdx.x + (blockIdx.y << 3);
  const int xq = lid & 7, y = lid >> 3;
  const int qt = (y & 32) ? (7 - xq) : xq;
  const int b = y >> 4, h = y & 15;

  const unsigned short* qg = qkv + (size_t)b * 1024 * 3072 + h * 64;
  const unsigned short* kg = qg + 1024;
  const unsigned short* vg = qg + 2048;

  #pragma unroll
  for (int i = 0; i < 4; i++) {
    const int idx = tid + i * 256;
    rps[idx & 1023] = rel_pos[h * 2048 + (idx & 1023)] * 1.44269504f;
  }

  const int sr  = tid >> 3;
  const int cg8 = ((tid & 7) ^ (sr & 7)) << 3;
  #pragma unroll
  for (int it = 0; it < 4; it++)
    cp16(qg + (size_t)(qt * 128 + sr + it * 32) * 3072 + cg8, &Qs[(tid + it * 256) * 8]);
  __syncthreads();   // full drain once (prologue only)

  bf16x8 qf[2][2];
  #pragma unroll
  for (int mt = 0; mt < 2; mt++)
    #pragma unroll
    for (int ks = 0; ks < 2; ks++)
      qf[mt][ks] = *(const bf16x8*)&Qs[(wave*32 + mt*16 + c)*64 + ((((ks<<2)+q) ^ (c & 7)) << 3)];

  const f32x4 fzero = {0.f, 0.f, 0.f, 0.f};
  f32x4 O[2][4];
  float l_i[2][4];
  #pragma unroll
  for (int mt = 0; mt < 2; mt++) {
    #pragma unroll
    for (int r = 0; r < 4; r++) l_i[mt][r] = 0.f;
    #pragma unroll
    for (int dt = 0; dt < 4; dt++) O[mt][dt] = fzero;
  }

  unsigned short* Pw = &Ps[wave][0];
  const int i_base = qt * 128 + wave * 32;
  const int vrow = tid & 63, d0 = (tid >> 6) << 4;
  const int vchunk = vrow >> 3, vlo = vrow & 7;

  const float sc = 0.125f * 1.44269504f;
  const int kdiag = qt << 1;
  const int nkt = (qt + 1) * 2;

  union VReg { int4 v; unsigned short u[8]; };
  VReg v0a, v0b, v1a, v1b;    // ping-pong: set kt&1

  auto issueK = [&](int kt) {
    unsigned short* Kb = &Ks[(kt % 3) * 4096];
    cp16(kg + (size_t)(kt * 64 + sr) * 3072 + cg8, Kb + tid * 8);
    cp16(kg + (size_t)(kt * 64 + sr + 32) * 3072 + cg8, Kb + (tid + 256) * 8);
  };

  // prologue: K(0), V(0), K(1)  (order matters for vmcnt accounting)
  issueK(0);
  {
    const unsigned short* vrp = vg + (size_t)(0 * 64 + vrow) * 3072 + d0;
    v0a.v = *(const int4*)vrp;
    v0b.v = *(const int4*)(vrp + 8);
  }
  issueK(1);

  for (int kt = 0; kt < nkt; kt++) {
    // prefetch V(kt+1) into the other reg set
    if (kt + 1 < nkt) {
      const unsigned short* vrp = vg + (size_t)((kt + 1) * 64 + vrow) * 3072 + d0;
      if (kt & 1) { v0a.v = *(const int4*)vrp; v0b.v = *(const int4*)(vrp + 8); }
      else        { v1a.v = *(const int4*)vrp; v1b.v = *(const int4*)(vrp + 8); }
    }
    // drain K(kt) cp16s + V(kt) regs (K(kt+1), V(kt+1) stay in flight)
    if (kt + 1 < nkt) asm volatile("s_waitcnt vmcnt(4)" ::: "memory");
    else              asm volatile("s_waitcnt vmcnt(0)" ::: "memory");
    asm volatile("s_barrier" ::: "memory");
    if (kt + 2 < nkt) issueK(kt + 2);

    // transpose-write V(kt) into Vs[kt&1] (overlaps with QK^T below)
    {
      unsigned short* Vb = &Vs[(kt & 1) * 4096];
      const VReg& ra = (kt & 1) ? v1a : v0a;
      const VReg& rb = (kt & 1) ? v1b : v0b;
      #pragma unroll
      for (int j = 0; j < 8; j++) {
        const int pos = ((vchunk ^ j) << 3) + vlo;
        Vb[(d0 + j) * 64 + pos]     = ra.u[j];
        Vb[(d0 + 8 + j) * 64 + pos] = rb.u[j];
      }
    }

    // S = Q K^T  (from Ks[kt%3])
    const unsigned short* Kb = &Ks[(kt % 3) * 4096];
    f32x4 S[2][4];
    #pragma unroll
    for (int mt = 0; mt < 2; mt++)
      #pragma unroll
      for (int nt = 0; nt < 4; nt++) S[mt][nt] = fzero;
    #pragma unroll
    for (int ks = 0; ks < 2; ks++) {
      const int sw = (((ks << 2) + q) ^ (c & 7)) << 3;
      bf16x8 kb[4];
      #pragma unroll
      for (int nt = 0; nt < 4; nt++) kb[nt] = *(const bf16x8*)&Kb[(nt*16 + c)*64 + sw];
      #pragma unroll
      for (int mt = 0; mt < 2; mt++)
        #pragma unroll
        for (int nt = 0; nt < 4; nt++)
          S[mt][nt] = __builtin_amdgcn_mfma_f32_16x16x32_bf16(qf[mt][ks], kb[nt], S[mt][nt], 0, 0, 0);
    }

    // bias + exp2 (+ causal mask on diagonal tiles); per-lane partial sums
    if (kt < kdiag) {
      #pragma unroll
      for (int mt = 0; mt < 2; mt++) {
        #pragma unroll
        for (int r = 0; r < 4; r++) {
          const int i_ = i_base + mt * 16 + q * 4 + r;
          const int prow = (mt * 16 + q * 4 + r) * 64;
          const int rsw  = (q * 4 + r) & 7;
          float s = 0.f;
          #pragma unroll
          for (int nt = 0; nt < 4; nt++) {
            const int j_ = kt * 64 + nt * 16 + c;
            const float p = exp2f(fmaf(S[mt][nt][r], sc, rps[i_ - j_]));
            s += p;
            Pw[prow + ((((nt << 1) + (c >> 3)) ^ rsw) << 3) + (c & 7)] = f2bf_fast(p);
          }
          l_i[mt][r] += s;
        }
      }
    } else {
      #pragma unroll
      for (int mt = 0; mt < 2; mt++) {
        #pragma unroll
        for (int r = 0; r < 4; r++) {
          const int i_ = i_base + mt * 16 + q * 4 + r;
          const int prow = (mt * 16 + q * 4 + r) * 64;
          const int rsw  = (q * 4 + r) & 7;
          float s = 0.f;
          #pragma unroll
          for (int nt = 0; nt < 4; nt++) {
            const int j_ = kt * 64 + nt * 16 + c;
            const int d_ = i_ - j_;
            const float p = (d_ >= 0)
                ? exp2f(fmaf(S[mt][nt][r], sc, rps[d_ & 1023])) : 0.f;
            s += p;
            Pw[prow + ((((nt << 1) + (c >> 3)) ^ rsw) << 3) + (c & 7)] = f2bf_fast(p);
          }
          l_i[mt][r] += s;
        }
      }
    }

    // own Pw + V writes done, then make V writes visible to all waves
    asm volatile("s_waitcnt lgkmcnt(0)" ::: "memory");
    asm volatile("s_barrier" ::: "memory");

    // O += P V  (from Vs[kt&1])
    const unsigned short* Vb = &Vs[(kt & 1) * 4096];
    #pragma unroll
    for (int ks = 0; ks < 2; ks++) {
      const int sw = (((ks << 2) + q) ^ (c & 7)) << 3;
      bf16x8 pa[2], vb[4];
      #pragma unroll
      for (int mt = 0; mt < 2; mt++) pa[mt] = *(const bf16x8*)&Pw[(mt*16 + c)*64 + sw];
      #pragma unroll
      for (int dt = 0; dt < 4; dt++) vb[dt] = *(const bf16x8*)&Vb[(dt*16 + c)*64 + sw];
      #pragma unroll
      for (int mt = 0; mt < 2; mt++)
        #pragma unroll
        for (int dt = 0; dt < 4; dt++)
          O[mt][dt] = __builtin_amdgcn_mfma_f32_16x16x32_bf16(pa[mt], vb[dt], O[mt][dt], 0, 0, 0);
    }
  }

  #pragma unroll
  for (int mt = 0; mt < 2; mt++) {
    #pragma unroll
    for (int r = 0; r < 4; r++) {
      float l = l_i[mt][r];
      l += __shfl_xor(l, 1, 64);
      l += __shfl_xor(l, 2, 64);
      l += __shfl_xor(l, 4, 64);
      l += __shfl_xor(l, 8, 64);
      const float inv = 1.0f / l;
      const int i_ = i_base + mt * 16 + q * 4 + r;
      unsigned short* orow = o + (size_t)(b * 1024 + i_) * 1024 + h * 64 + c;
      #pragma unroll
      for (int dt = 0; dt < 4; dt++) orow[dt * 16] = f2bf(O[mt][dt][r] * inv);
    }
  }
}

// ---------------------------------------------------------------------------
// Launch
// ---------------------------------------------------------------------------
extern "C" void kernel_launch(void* const* d_in, const int* in_sizes, int n_in,
                              void* d_out, int out_size, void* d_ws, size_t ws_size,
                              hipStream_t stream) {
  (void)in_sizes; (void)n_in; (void)out_size; (void)ws_size;
  const float* x    = (const float*)d_in[0];
  const float* rel  = (const float*)d_in[1];
  const float* ipw  = (const float*)d_in[2];
  const float* ipb  = (const float*)d_in[3];
  const float* outw = (const float*)d_in[4];
  const float* outb = (const float*)d_in[5];
  const float* w1   = (const float*)d_in[6];
  const float* b1   = (const float*)d_in[7];
  const float* w2   = (const float*)d_in[8];
  const float* b2   = (const float*)d_in[9];
  const float* ln1g = (const float*)d_in[10];
  const float* ln1b = (const float*)d_in[11];
  const float* ln2g = (const float*)d_in[12];
  const float* ln2b = (const float*)d_in[13];

  // workspace layout (elements)
  unsigned short* ipw_b  = (unsigned short*)d_ws;            // 3072*1024
  unsigned short* outw_b = ipw_b  + (size_t)3072 * 1024;     // 1024*1024
  unsigned short* w1_b   = outw_b + (size_t)1024 * 1024;     // 4096*1024
  unsigned short* w2_b   = w1_b   + (size_t)4096 * 1024;     // 1024*4096
  unsigned short* xn     = w2_b   + (size_t)1024 * 4096;     // 4096*1024
  unsigned short* qkvb   = xn     + (size_t)4096 * 1024;     // 4096*3072
  unsigned short* ob     = qkvb   + (size_t)4096 * 3072;     // 4096*1024
  float*          x2     = (float*)(ob + (size_t)4096 * 1024);          // 4096*1024 f32
  unsigned short* xm     = (unsigned short*)(x2 + (size_t)4096 * 1024); // 4096*1024
  unsigned short* hb     = xm + (size_t)4096 * 1024;         // 4096*4096

  cvt_all<<<12288, 256, 0, stream>>>(ipw, outw, w1, w2, ipw_b, outw_b, w1_b, w2_b);

  // ln1 + seed x2 = x + outb
  ln_bf16_seed<<<4096, 256, 0, stream>>>(x, ln1g, ln1b, xn, outb, x2);

  // QKV proj: NBUF=3 (48 KB LDS) -> 3 blocks/CU, grid 768 = 3/CU exact
  gemm_k<0, 3, 3><<<dim3(32, 24), 256, 0, stream>>>(xn, ipw_b, ipb, qkvb, 3072, 1024);

  attn_flash<<<dim3(8, 64), 256, 0, stream>>>(qkvb, rel, ob);

  // attn out proj: x2 += ob @ outw^T  (split-K=2, atomic)
  gemm_splitk<3, 3><<<dim3(32, 8, 2), 256, 0, stream>>>(ob, outw_b, x2, 1024, 1024, 512);

  // ln2 + seed d_out = x2 + b2
  ln_bf16_seed<<<4096, 256, 0, stream>>>(x2, ln2g, ln2b, xm, b2, (float*)d_out);

  // MLP up: NBUF=2 (32 KB LDS) -> 4 blocks/CU, grid 1024 = 4/CU exact
  gemm_k<2, 2, 4><<<dim3(32, 32), 256, 0, stream>>>(xm, w1_b, b1, hb, 4096, 1024);

  // MLP down: d_out += hb @ w2^T  (split-K=3 -> 768 blocks = 3/CU exact)
  gemm_splitk<3, 3><<<dim3(32, 8, 3), 256, 0, stream>>>(hb, w2_b, (float*)d_out, 1024, 4096, 1376);
}